// Round 8
// baseline (613.927 us; speedup 1.0000x reference)
//
#include <hip/hip_runtime.h>
#include <stdint.h>
#include <stddef.h>

typedef __bf16 bf16;
typedef __bf16 bf16x8 __attribute__((ext_vector_type(8)));
typedef float f32x4 __attribute__((ext_vector_type(4)));
typedef float f32x16 __attribute__((ext_vector_type(16)));

#define AST 264                  // LDS act row stride (528B: 16B-aligned, 4-bank skew)
#define BNI 0.9999950000374996f // 1/sqrt(1+1e-5)

// dynamic-LDS layout (bytes)
#define OFF_ACT   0
#define OFF_POOL  (160*AST*2)             // 84480
#define OFF_T2    (OFF_POOL + 32*AST*2)   // 101376
#define OFF_MASK  (OFF_T2 + 8*256*4)      // 109568
#define OFF_VALID (OFF_MASK + 160*4)      // 110208
#define LDS_TOTAL (OFF_VALID + 32)        // 110240

// ws layout (bf16 elems)
#define WS_PRE_W0 0
#define WS_PRE_W1 8192
#define WS_PRE_W2 73728
#define WS_MLP_W0 139264
#define WS_MLP_W1 270336
#define WS_MLP_W2 335872
#define WS_OUT_W0 401408
#define WS_OUT_W1 466944

__device__ __forceinline__ bf16 f2b(float f){
  unsigned int i = __builtin_bit_cast(unsigned int, f);
  unsigned int r = i + 0x7fffu + ((i >> 16) & 1u);
  unsigned short h = (unsigned short)(r >> 16);
  return __builtin_bit_cast(bf16, h);
}
__device__ __forceinline__ float b2f(bf16 x){
  unsigned short u = __builtin_bit_cast(unsigned short, x);
  union { unsigned int i; float f; } v; v.i = ((unsigned int)u) << 16; return v.f;
}
__device__ __forceinline__ bf16x8 ld8f(const float* p){
  f32x4 a = *(const f32x4*)p;
  f32x4 b = *(const f32x4*)(p + 4);
  bf16x8 r;
  #pragma unroll
  for (int j = 0; j < 4; ++j){ r[j] = f2b(a[j]); r[4+j] = f2b(b[j]); }
  return r;
}

// ---------------- prep: fp32 weights -> bf16 in ws ----------------
__global__ __launch_bounds__(256)
void prep_kernel(const float* s0, const float* s1, const float* s2, const float* s3,
                 const float* s4, const float* s5, const float* s6, const float* s7,
                 bf16* dst)
{
  const int offs[8] = {WS_PRE_W0, WS_PRE_W1, WS_PRE_W2, WS_MLP_W0,
                       WS_MLP_W1, WS_MLP_W2, WS_OUT_W0, WS_OUT_W1};
  const int sz[8]   = {8192, 65536, 65536, 131072, 65536, 65536, 65536, 65536};
  int r = blockIdx.y;
  const float* src = s0;
  if (r == 1) src = s1; else if (r == 2) src = s2; else if (r == 3) src = s3;
  else if (r == 4) src = s4; else if (r == 5) src = s5; else if (r == 6) src = s6;
  else if (r == 7) src = s7;
  int i = (blockIdx.x*256 + threadIdx.x)*8;
  if (i < sz[r]){
    bf16x8 v = ld8f(src + i);
    *(bf16x8*)&dst[offs[r] + i] = v;
  }
}

// barrier-free 256->256 layer, in-place on the wave's own 32 rows.
// B loaded inline per 32-col tile: 16 frags (64 VGPRs) live at once, no dbuf -> no spill.
template<int RELU, int MASK, int ADDT2>
__device__ __forceinline__ void layer256(
    bf16* sAct, const float* sT2v, const float* sMaskF,
    const bf16* W, int ldW, const float* gptr, const float* bptr,
    int rowBase, int lane32, int hi)
{
  bf16x8 A[16];
  #pragma unroll
  for (int k = 0; k < 16; ++k)
    A[k] = *(const bf16x8*)&sAct[(rowBase + lane32)*AST + k*16 + 8*hi];

  float mk[16]; int pp[16];
  #pragma unroll
  for (int reg = 0; reg < 16; ++reg){
    int r = (reg & 3) + 8*(reg >> 2) + 4*hi;        // verified C/D row map (m74/m101)
    if (MASK)  mk[reg] = sMaskF[rowBase + r];
    if (ADDT2) pp[reg] = (rowBase + r)/20;
  }

  #pragma unroll 1
  for (int nt = 0; nt < 8; ++nt){
    const bf16* p = W + (size_t)(nt*32 + lane32)*ldW + 8*hi;
    bf16x8 B[16];
    #pragma unroll
    for (int k = 0; k < 16; ++k) B[k] = *(const bf16x8*)(p + k*16);
    f32x16 acc = {};
    #pragma unroll
    for (int k = 0; k < 16; ++k)
      acc = __builtin_amdgcn_mfma_f32_32x32x16_bf16(A[k], B[k], acc, 0, 0, 0);
    int col = nt*32 + lane32;
    float s  = gptr ? (gptr[col]*BNI) : 1.0f;
    float bb = bptr[col];
    #pragma unroll
    for (int reg = 0; reg < 16; ++reg){
      int r = (reg & 3) + 8*(reg >> 2) + 4*hi;
      float v = acc[reg];
      if (ADDT2) v += sT2v[pp[reg]*256 + col];
      v = v*s + bb;
      if (RELU) v = fmaxf(v, 0.0f);
      if (MASK) v *= mk[reg];
      sAct[(rowBase + r)*AST + col] = f2b(v);
    }
  }
}

// max over 20 mask-zeroed rows per polyline -> sPool rows 0..7 (rows 8..31: stale/poison
// bytes are finite bf16 (0xAAAA ok); MFMA D-row r depends only on A-row r -> harmless)
__device__ __forceinline__ void poolMaxV(const bf16* sAct, bf16* sPool, int tid){
  if (tid < 256){
    int poly = tid >> 5, c = tid & 31;
    float m[8];
    bf16x8 v0 = *(const bf16x8*)&sAct[(poly*20)*AST + c*8];
    #pragma unroll
    for (int j = 0; j < 8; ++j) m[j] = b2f(v0[j]);
    #pragma unroll
    for (int r = 1; r < 20; ++r){
      bf16x8 v = *(const bf16x8*)&sAct[(poly*20 + r)*AST + c*8];
      #pragma unroll
      for (int j = 0; j < 8; ++j) m[j] = fmaxf(m[j], b2f(v[j]));
    }
    bf16x8 o;
    #pragma unroll
    for (int j = 0; j < 8; ++j) o[j] = f2b(m[j]);
    *(bf16x8*)&sPool[poly*AST + c*8] = o;
  }
}

__global__ __launch_bounds__(320, 1)
void traj_kernel(const float* __restrict__ poly, const int* __restrict__ maskp,
                 const float* pre_g0, const float* pre_b0,
                 const float* pre_g1, const float* pre_b1,
                 const float* pre_bias2,
                 const float* mlp_g0, const float* mlp_b0,
                 const float* mlp_g1, const float* mlp_b1,
                 const float* mlp_bias2,
                 const float* out_b0, const float* out_b1,
                 const bf16* __restrict__ ws,
                 float* __restrict__ outp)
{
  extern __shared__ char smem[];
  bf16*  sAct    = (bf16*)(smem + OFF_ACT);    // 160 x 264
  bf16*  sPool   = (bf16*)(smem + OFF_POOL);   // 32 x 264 A-tile (rows 0..7 valid)
  float* sT2v    = (float*)(smem + OFF_T2);    // 8 x 256
  float* sMaskF  = (float*)(smem + OFF_MASK);  // 160
  float* sValidF = (float*)(smem + OFF_VALID); // 8

  const int tid = threadIdx.x;
  const int w = tid >> 6, L = tid & 63, lane32 = L & 31, hi = L >> 5;
  const int rowBase = w*32;
  const int blk = blockIdx.x;

  const bf16* pw0b = ws + WS_PRE_W0;
  const bf16* pw1b = ws + WS_PRE_W1;
  const bf16* pw2b = ws + WS_PRE_W2;
  const bf16* mw0b = ws + WS_MLP_W0;
  const bf16* mw1b = ws + WS_MLP_W1;
  const bf16* mw2b = ws + WS_MLP_W2;
  const bf16* ow0b = ws + WS_OUT_W0;
  const bf16* ow1b = ws + WS_OUT_W1;

  // ---- phase 0: load fp32 input (160x32) + int32 mask ----
  {
    #pragma unroll
    for (int it = 0; it < 2; ++it){
      int idx = tid + it*320;                 // 640 chunks = 160 rows x 4
      int row = idx >> 2, ch = idx & 3;
      bf16x8 v = ld8f(poly + (size_t)(blk*160 + row)*32 + ch*8);
      *(bf16x8*)&sAct[row*AST + ch*8] = v;
    }
    if (tid < 160) sMaskF[tid] = (maskp[blk*160 + tid] != 0) ? 1.0f : 0.0f;
  }
  __syncthreads();                            // B1
  if (tid < 8){
    float v = 0.0f;
    #pragma unroll
    for (int r = 0; r < 20; ++r) v = fmaxf(v, sMaskF[tid*20 + r]);
    sValidF[tid] = v;                         // consumed in out1 (many barriers later)
  }

  // ---- pre0: K=32 (2 k-steps), B direct from ws ----
  {
    bf16x8 a0 = *(const bf16x8*)&sAct[(rowBase + lane32)*AST + 8*hi];
    bf16x8 a1 = *(const bf16x8*)&sAct[(rowBase + lane32)*AST + 16 + 8*hi];
    #pragma unroll 1
    for (int nt = 0; nt < 8; ++nt){
      const bf16* p = pw0b + (size_t)(nt*32 + lane32)*32 + 8*hi;
      bf16x8 b0 = *(const bf16x8*)p;
      bf16x8 b1 = *(const bf16x8*)(p + 16);
      f32x16 acc = {};
      acc = __builtin_amdgcn_mfma_f32_32x32x16_bf16(a0, b0, acc, 0, 0, 0);
      acc = __builtin_amdgcn_mfma_f32_32x32x16_bf16(a1, b1, acc, 0, 0, 0);
      int col = nt*32 + lane32;
      float s = pre_g0[col]*BNI, bb = pre_b0[col];
      #pragma unroll
      for (int reg = 0; reg < 16; ++reg){
        int r = (reg & 3) + 8*(reg >> 2) + 4*hi;
        float v = fmaxf(acc[reg]*s + bb, 0.0f);
        sAct[(rowBase + r)*AST + col] = f2b(v);
      }
    }
  }

  // ---- pre1, pre2 (barrier-free, own rows) ----
  layer256<1,0,0>(sAct, sT2v, sMaskF, pw1b, 256, pre_g1, pre_b1, rowBase, lane32, hi);
  layer256<0,1,0>(sAct, sT2v, sMaskF, pw2b, 256, nullptr, pre_bias2, rowBase, lane32, hi);

  __syncthreads();                            // B2: all pre2 writes done
  poolMaxV(sAct, sPool, tid);
  __syncthreads();                            // B3: pool1 visible

  // ---- t2 = pooled @ mlp_w0[:,256:]^T ----
  {
    bf16x8 A[16];
    #pragma unroll
    for (int k = 0; k < 16; ++k)
      A[k] = *(const bf16x8*)&sPool[lane32*AST + k*16 + 8*hi];
    #pragma unroll 1
    for (int nt = w; nt < 8; nt += 5){
      const bf16* p = mw0b + (size_t)(nt*32 + lane32)*512 + 256 + 8*hi;
      f32x16 acc = {};
      #pragma unroll
      for (int k = 0; k < 16; ++k){
        bf16x8 b = *(const bf16x8*)(p + k*16);
        acc = __builtin_amdgcn_mfma_f32_32x32x16_bf16(A[k], b, acc, 0, 0, 0);
      }
      int col = nt*32 + lane32;
      #pragma unroll
      for (int reg = 0; reg < 4; ++reg)
        sT2v[(reg + 4*hi)*256 + col] = acc[reg];
    }
  }
  __syncthreads();                            // B4: sT2v ready

  // ---- mlp0 (x-half + t2), mlp1, mlp2 (barrier-free) ----
  layer256<1,0,1>(sAct, sT2v, sMaskF, mw0b, 512, mlp_g0, mlp_b0, rowBase, lane32, hi);
  layer256<1,0,0>(sAct, sT2v, sMaskF, mw1b, 256, mlp_g1, mlp_b1, rowBase, lane32, hi);
  layer256<0,1,0>(sAct, sT2v, sMaskF, mw2b, 256, nullptr, mlp_bias2, rowBase, lane32, hi);

  __syncthreads();                            // B5: all mlp2 writes done
  poolMaxV(sAct, sPool, tid);
  __syncthreads();                            // B6: pool2 visible

  // ---- out0: y = relu(buf @ out_w0^T + b0), held in regs across barrier ----
  float yv[2][4]; int myn[2]; int ncnt = 0;
  {
    bf16x8 A[16];
    #pragma unroll
    for (int k = 0; k < 16; ++k)
      A[k] = *(const bf16x8*)&sPool[lane32*AST + k*16 + 8*hi];
    #pragma unroll 1
    for (int nt = w; nt < 8; nt += 5){
      const bf16* p = ow0b + (size_t)(nt*32 + lane32)*256 + 8*hi;
      f32x16 acc = {};
      #pragma unroll
      for (int k = 0; k < 16; ++k){
        bf16x8 b = *(const bf16x8*)(p + k*16);
        acc = __builtin_amdgcn_mfma_f32_32x32x16_bf16(A[k], b, acc, 0, 0, 0);
      }
      int col = nt*32 + lane32;
      #pragma unroll
      for (int reg = 0; reg < 4; ++reg)
        yv[ncnt][reg] = fmaxf(acc[reg] + out_b0[col], 0.0f);
      myn[ncnt++] = nt;
    }
  }
  __syncthreads();                            // B7: all pooled A-reads done
  for (int j = 0; j < ncnt; ++j){
    int col = myn[j]*32 + lane32;
    #pragma unroll
    for (int reg = 0; reg < 4; ++reg)
      sPool[(reg + 4*hi)*AST + col] = f2b(yv[j][reg]);
  }
  __syncthreads();                            // B8: y visible

  // ---- out1: z = (y @ out_w1^T + b1) * valid -> global fp32 ----
  {
    bf16x8 A[16];
    #pragma unroll
    for (int k = 0; k < 16; ++k)
      A[k] = *(const bf16x8*)&sPool[lane32*AST + k*16 + 8*hi];
    #pragma unroll 1
    for (int nt = w; nt < 8; nt += 5){
      const bf16* p = ow1b + (size_t)(nt*32 + lane32)*256 + 8*hi;
      f32x16 acc = {};
      #pragma unroll
      for (int k = 0; k < 16; ++k){
        bf16x8 b = *(const bf16x8*)(p + k*16);
        acc = __builtin_amdgcn_mfma_f32_32x32x16_bf16(A[k], b, acc, 0, 0, 0);
      }
      int col = nt*32 + lane32;
      #pragma unroll
      for (int reg = 0; reg < 4; ++reg){
        int r = reg + 4*hi;
        outp[(size_t)(blk*8 + r)*256 + col] = (acc[reg] + out_b1[col]) * sValidF[r];
      }
    }
  }
}

extern "C" void kernel_launch(void* const* d_in, const int* in_sizes, int n_in,
                              void* d_out, int out_size, void* d_ws, size_t ws_size,
                              hipStream_t stream)
{
  const float* poly      = (const float*)d_in[0];
  const int*   maskp     = (const int*)  d_in[1];
  const float* pre_w0    = (const float*)d_in[2];
  const float* pre_g0    = (const float*)d_in[3];
  const float* pre_b0    = (const float*)d_in[4];
  const float* pre_w1    = (const float*)d_in[5];
  const float* pre_g1    = (const float*)d_in[6];
  const float* pre_b1    = (const float*)d_in[7];
  const float* pre_w2    = (const float*)d_in[8];
  const float* pre_bias2 = (const float*)d_in[9];
  const float* mlp_w0    = (const float*)d_in[10];
  const float* mlp_g0    = (const float*)d_in[11];
  const float* mlp_b0    = (const float*)d_in[12];
  const float* mlp_w1    = (const float*)d_in[13];
  const float* mlp_g1    = (const float*)d_in[14];
  const float* mlp_b1    = (const float*)d_in[15];
  const float* mlp_w2    = (const float*)d_in[16];
  const float* mlp_bias2 = (const float*)d_in[17];
  const float* out_w0    = (const float*)d_in[18];
  const float* out_b0    = (const float*)d_in[19];
  const float* out_w1    = (const float*)d_in[20];
  const float* out_b1    = (const float*)d_in[21];

  bf16* ws = (bf16*)d_ws;   // 1,064,960 B of ws used

  (void)hipFuncSetAttribute((const void*)&traj_kernel,
                            hipFuncAttributeMaxDynamicSharedMemorySize, LDS_TOTAL);

  prep_kernel<<<dim3(64, 8), dim3(256), 0, stream>>>(
      pre_w0, pre_w1, pre_w2, mlp_w0, mlp_w1, mlp_w2, out_w0, out_w1, ws);

  traj_kernel<<<dim3(1024), dim3(320), LDS_TOTAL, stream>>>(
      poly, maskp,
      pre_g0, pre_b0, pre_g1, pre_b1, pre_bias2,
      mlp_g0, mlp_b0, mlp_g1, mlp_b1, mlp_bias2,
      out_b0, out_b1,
      ws, (float*)d_out);
}

// Round 9
// 350.025 us; speedup vs baseline: 1.7540x; 1.7540x over previous
//
#include <hip/hip_runtime.h>
#include <stdint.h>
#include <stddef.h>

typedef __bf16 bf16;
typedef __bf16 bf16x8 __attribute__((ext_vector_type(8)));
typedef float f32x4 __attribute__((ext_vector_type(4)));
typedef float f32x16 __attribute__((ext_vector_type(16)));

#define AST 264                  // sAct row stride (528B: 16B-aligned, 4-bank skew)
#define BNI 0.9999950000374996f // 1/sqrt(1+1e-5)

// dynamic-LDS layout (bytes)
#define OFF_ACT   0
#define OFF_W0    (160*AST*2)            // 84480
#define OFF_W1    (OFF_W0 + 32768)       // 117248
#define OFF_T2    (OFF_W1 + 32768)       // 150016
#define OFF_MASK  (OFF_T2 + 8*256*4)     // 158208
#define OFF_VALID (OFF_MASK + 160*4)     // 158848
#define LDS_TOTAL (OFF_VALID + 32)       // 158880  (<= 160 KiB)

// ws layout (bf16 elems)
#define WS_PRE_W0 0
#define WS_PRE_W1 8192
#define WS_PRE_W2 73728
#define WS_MLP_W0 139264
#define WS_MLP_W1 270336
#define WS_MLP_W2 335872
#define WS_OUT_W0 401408
#define WS_OUT_W1 466944

__device__ __forceinline__ bf16 f2b(float f){
  unsigned int i = __builtin_bit_cast(unsigned int, f);
  unsigned int r = i + 0x7fffu + ((i >> 16) & 1u);
  unsigned short h = (unsigned short)(r >> 16);
  return __builtin_bit_cast(bf16, h);
}
__device__ __forceinline__ float b2f(bf16 x){
  unsigned short u = __builtin_bit_cast(unsigned short, x);
  union { unsigned int i; float f; } v; v.i = ((unsigned int)u) << 16; return v.f;
}
__device__ __forceinline__ bf16x8 ld8f(const float* p){
  f32x4 a = *(const f32x4*)p;
  f32x4 b = *(const f32x4*)(p + 4);
  bf16x8 r;
  #pragma unroll
  for (int j = 0; j < 4; ++j){ r[j] = f2b(a[j]); r[4+j] = f2b(b[j]); }
  return r;
}

// ---------------- prep: fp32 weights -> bf16 in ws ----------------
__global__ __launch_bounds__(256)
void prep_kernel(const float* s0, const float* s1, const float* s2, const float* s3,
                 const float* s4, const float* s5, const float* s6, const float* s7,
                 bf16* dst)
{
  const int offs[8] = {WS_PRE_W0, WS_PRE_W1, WS_PRE_W2, WS_MLP_W0,
                       WS_MLP_W1, WS_MLP_W2, WS_OUT_W0, WS_OUT_W1};
  const int sz[8]   = {8192, 65536, 65536, 131072, 65536, 65536, 65536, 65536};
  int r = blockIdx.y;
  const float* src = s0;
  if (r == 1) src = s1; else if (r == 2) src = s2; else if (r == 3) src = s3;
  else if (r == 4) src = s4; else if (r == 5) src = s5; else if (r == 6) src = s6;
  else if (r == 7) src = s7;
  int i = (blockIdx.x*256 + threadIdx.x)*8;
  if (i < sz[r]){
    bf16x8 v = ld8f(src + i);
    *(bf16x8*)&dst[offs[r] + i] = v;
  }
}

// ---- weight-quarter staging: 64 rows x 256 cols, XOR-swizzled chunks ----
// phys: row r, chunk c (8 elems) at r*256 + ((c ^ (r&31))*8)
__device__ __forceinline__ void stageLoad(bf16x8* v, const bf16* W, int ldW, int row0, int tid){
  #pragma unroll
  for (int i = 0; i < 7; ++i){
    int id = tid + i*320;
    if (id < 2048){
      int r = id >> 5, c = id & 31;
      v[i] = *(const bf16x8*)(W + (size_t)(row0 + r)*ldW + c*8);
    }
  }
}
__device__ __forceinline__ void stageStore(const bf16x8* v, bf16* wbuf, int tid){
  #pragma unroll
  for (int i = 0; i < 7; ++i){
    int id = tid + i*320;
    if (id < 2048){
      int r = id >> 5, c = id & 31;
      *(bf16x8*)&wbuf[r*256 + ((c ^ (r & 31))*8)] = v[i];
    }
  }
}

// compute one quarter (2 nt tiles of 32 cols) from staged LDS weights
template<int RELU, int MASK, int ADDT2>
__device__ __forceinline__ void computeQ(
    int q, const bf16* wbuf, const bf16x8* A,
    bf16* sAct, const float* sT2v,
    const float* gptr, const float* bptr, const float* mk, const int* pp,
    int rowBase, int lane32, int hi)
{
  #pragma unroll
  for (int half = 0; half < 2; ++half){
    int nt = q*2 + half;
    const bf16* base = wbuf + (half*32 + lane32)*256;
    f32x16 acc = {};
    #pragma unroll
    for (int k = 0; k < 16; ++k){
      int c = k*2 + hi;
      bf16x8 b = *(const bf16x8*)(base + ((c ^ lane32)*8));
      acc = __builtin_amdgcn_mfma_f32_32x32x16_bf16(A[k], b, acc, 0, 0, 0);
    }
    int col = nt*32 + lane32;
    float s  = gptr ? (gptr[col]*BNI) : 1.0f;
    float bb = bptr[col];
    #pragma unroll
    for (int reg = 0; reg < 16; ++reg){
      int r = (reg & 3) + 8*(reg >> 2) + 4*hi;    // verified C/D row map
      float v = acc[reg];
      if (ADDT2) v += sT2v[pp[reg]*256 + col];
      v = v*s + bb;
      if (RELU) v = fmaxf(v, 0.0f);
      if (MASK) v *= mk[reg];
      sAct[(rowBase + r)*AST + col] = f2b(v);
    }
  }
}

// 256->256 layer with LDS-staged weights, dbuf quarters, 1 barrier/quarter
template<int RELU, int MASK, int ADDT2>
__device__ __forceinline__ void layer256s(
    bf16* sAct, bf16* wb0, bf16* wb1, const float* sT2v, const float* sMaskF,
    const bf16* W, int ldW, const float* gptr, const float* bptr,
    int rowBase, int lane32, int hi, int tid)
{
  bf16x8 A[16];
  #pragma unroll
  for (int k = 0; k < 16; ++k)
    A[k] = *(const bf16x8*)&sAct[(rowBase + lane32)*AST + k*16 + 8*hi];  // own rows

  float mk[16]; int pp[16];
  #pragma unroll
  for (int reg = 0; reg < 16; ++reg){
    int r = (reg & 3) + 8*(reg >> 2) + 4*hi;
    if (MASK)  mk[reg] = sMaskF[rowBase + r];
    if (ADDT2) pp[reg] = (rowBase + r)/20;
  }

  bf16x8 st[7];
  stageLoad(st, W, ldW, 0, tid);
  stageStore(st, wb0, tid);
  __syncthreads();
  #pragma unroll
  for (int q = 0; q < 4; ++q){
    bf16* cur = (q & 1) ? wb1 : wb0;
    bf16* nxt = (q & 1) ? wb0 : wb1;
    if (q < 3) stageLoad(st, W, ldW, (q + 1)*64, tid);   // loads fly under compute
    computeQ<RELU,MASK,ADDT2>(q, cur, A, sAct, sT2v, gptr, bptr, mk, pp,
                              rowBase, lane32, hi);
    if (q < 3) stageStore(st, nxt, tid);                 // vmcnt waits land here
    __syncthreads();
  }
}

// max over 20 mask-zeroed rows per polyline -> sPool rows 0..7 (rows 8..31 garbage ok)
__device__ __forceinline__ void poolMaxV(const bf16* sAct, bf16* sPool, int tid){
  if (tid < 256){
    int poly = tid >> 5, c = tid & 31;
    float m[8];
    bf16x8 v0 = *(const bf16x8*)&sAct[(poly*20)*AST + c*8];
    #pragma unroll
    for (int j = 0; j < 8; ++j) m[j] = b2f(v0[j]);
    #pragma unroll
    for (int r = 1; r < 20; ++r){
      bf16x8 v = *(const bf16x8*)&sAct[(poly*20 + r)*AST + c*8];
      #pragma unroll
      for (int j = 0; j < 8; ++j) m[j] = fmaxf(m[j], b2f(v[j]));
    }
    bf16x8 o;
    #pragma unroll
    for (int j = 0; j < 8; ++j) o[j] = f2b(m[j]);
    *(bf16x8*)&sPool[poly*AST + c*8] = o;
  }
}

__global__ __launch_bounds__(320, 1)
void traj_kernel(const float* __restrict__ poly, const int* __restrict__ maskp,
                 const float* pre_g0, const float* pre_b0,
                 const float* pre_g1, const float* pre_b1,
                 const float* pre_bias2,
                 const float* mlp_g0, const float* mlp_b0,
                 const float* mlp_g1, const float* mlp_b1,
                 const float* mlp_bias2,
                 const float* out_b0, const float* out_b1,
                 const bf16* __restrict__ ws,
                 float* __restrict__ outp)
{
  extern __shared__ char smem[];
  bf16*  sAct    = (bf16*)(smem + OFF_ACT);    // 160 x 264
  bf16*  wb0     = (bf16*)(smem + OFF_W0);     // 64 x 256 swizzled
  bf16*  wb1     = (bf16*)(smem + OFF_W1);
  float* sT2v    = (float*)(smem + OFF_T2);    // 8 x 256
  float* sMaskF  = (float*)(smem + OFF_MASK);  // 160
  float* sValidF = (float*)(smem + OFF_VALID); // 8
  bf16*  sPool   = wb0;                        // pooled A-tile aliases wb0 (32 x 264)

  const int tid = threadIdx.x;
  const int w = tid >> 6, L = tid & 63, lane32 = L & 31, hi = L >> 5;
  const int rowBase = w*32;
  const int blk = blockIdx.x;

  const bf16* pw0b = ws + WS_PRE_W0;
  const bf16* pw1b = ws + WS_PRE_W1;
  const bf16* pw2b = ws + WS_PRE_W2;
  const bf16* mw0b = ws + WS_MLP_W0;
  const bf16* mw1b = ws + WS_MLP_W1;
  const bf16* mw2b = ws + WS_MLP_W2;
  const bf16* ow0b = ws + WS_OUT_W0;
  const bf16* ow1b = ws + WS_OUT_W1;

  // ---- phase 0: load fp32 input (160x32) + int32 mask ----
  {
    #pragma unroll
    for (int it = 0; it < 2; ++it){
      int idx = tid + it*320;                 // 640 chunks = 160 rows x 4
      int row = idx >> 2, ch = idx & 3;
      bf16x8 v = ld8f(poly + (size_t)(blk*160 + row)*32 + ch*8);
      *(bf16x8*)&sAct[row*AST + ch*8] = v;
    }
    if (tid < 160) sMaskF[tid] = (maskp[blk*160 + tid] != 0) ? 1.0f : 0.0f;
  }
  __syncthreads();
  if (tid < 8){
    float v = 0.0f;
    #pragma unroll
    for (int r = 0; r < 20; ++r) v = fmaxf(v, sMaskF[tid*20 + r]);
    sValidF[tid] = v;                         // consumed in out1
  }

  // ---- pre0: K=32 (2 k-steps), B direct from ws ----
  {
    bf16x8 a0 = *(const bf16x8*)&sAct[(rowBase + lane32)*AST + 8*hi];
    bf16x8 a1 = *(const bf16x8*)&sAct[(rowBase + lane32)*AST + 16 + 8*hi];
    #pragma unroll 1
    for (int nt = 0; nt < 8; ++nt){
      const bf16* p = pw0b + (size_t)(nt*32 + lane32)*32 + 8*hi;
      bf16x8 b0 = *(const bf16x8*)p;
      bf16x8 b1 = *(const bf16x8*)(p + 16);
      f32x16 acc = {};
      acc = __builtin_amdgcn_mfma_f32_32x32x16_bf16(a0, b0, acc, 0, 0, 0);
      acc = __builtin_amdgcn_mfma_f32_32x32x16_bf16(a1, b1, acc, 0, 0, 0);
      int col = nt*32 + lane32;
      float s = pre_g0[col]*BNI, bb = pre_b0[col];
      #pragma unroll
      for (int reg = 0; reg < 16; ++reg){
        int r = (reg & 3) + 8*(reg >> 2) + 4*hi;
        float v = fmaxf(acc[reg]*s + bb, 0.0f);
        sAct[(rowBase + r)*AST + col] = f2b(v);
      }
    }
  }
  __syncthreads();   // wb0 about to be written; also pre0 done (cheap safety)

  // ---- pre1, pre2 (LDS-staged) ----
  layer256s<1,0,0>(sAct, wb0, wb1, sT2v, sMaskF, pw1b, 256, pre_g1, pre_b1, rowBase, lane32, hi, tid);
  layer256s<0,1,0>(sAct, wb0, wb1, sT2v, sMaskF, pw2b, 256, nullptr, pre_bias2, rowBase, lane32, hi, tid);

  // (last layer barrier already synced) ---- pool 1 -> sPool (aliases wb0) ----
  poolMaxV(sAct, sPool, tid);
  __syncthreads();

  // ---- t2 = pooled @ mlp_w0[:,256:]^T (direct global) ----
  {
    bf16x8 A[16];
    #pragma unroll
    for (int k = 0; k < 16; ++k)
      A[k] = *(const bf16x8*)&sPool[lane32*AST + k*16 + 8*hi];
    #pragma unroll 1
    for (int nt = w; nt < 8; nt += 5){
      const bf16* p = mw0b + (size_t)(nt*32 + lane32)*512 + 256 + 8*hi;
      f32x16 acc = {};
      #pragma unroll
      for (int k = 0; k < 16; ++k){
        bf16x8 b = *(const bf16x8*)(p + k*16);
        acc = __builtin_amdgcn_mfma_f32_32x32x16_bf16(A[k], b, acc, 0, 0, 0);
      }
      int col = nt*32 + lane32;
      #pragma unroll
      for (int reg = 0; reg < 4; ++reg)
        sT2v[(reg + 4*hi)*256 + col] = acc[reg];
    }
  }
  __syncthreads();

  // ---- mlp0 (x-half + t2), mlp1, mlp2 (LDS-staged) ----
  layer256s<1,0,1>(sAct, wb0, wb1, sT2v, sMaskF, mw0b, 512, mlp_g0, mlp_b0, rowBase, lane32, hi, tid);
  layer256s<1,0,0>(sAct, wb0, wb1, sT2v, sMaskF, mw1b, 256, mlp_g1, mlp_b1, rowBase, lane32, hi, tid);
  layer256s<0,1,0>(sAct, wb0, wb1, sT2v, sMaskF, mw2b, 256, nullptr, mlp_bias2, rowBase, lane32, hi, tid);

  // ---- pool 2 ----
  poolMaxV(sAct, sPool, tid);
  __syncthreads();

  // ---- out0: y = relu(buf @ out_w0^T + b0), held in regs across barrier ----
  float yv[2][4]; int myn[2]; int ncnt = 0;
  {
    bf16x8 A[16];
    #pragma unroll
    for (int k = 0; k < 16; ++k)
      A[k] = *(const bf16x8*)&sPool[lane32*AST + k*16 + 8*hi];
    #pragma unroll 1
    for (int nt = w; nt < 8; nt += 5){
      const bf16* p = ow0b + (size_t)(nt*32 + lane32)*256 + 8*hi;
      f32x16 acc = {};
      #pragma unroll
      for (int k = 0; k < 16; ++k){
        bf16x8 b = *(const bf16x8*)(p + k*16);
        acc = __builtin_amdgcn_mfma_f32_32x32x16_bf16(A[k], b, acc, 0, 0, 0);
      }
      int col = nt*32 + lane32;
      #pragma unroll
      for (int reg = 0; reg < 4; ++reg)
        yv[ncnt][reg] = fmaxf(acc[reg] + out_b0[col], 0.0f);
      myn[ncnt++] = nt;
    }
  }
  __syncthreads();                            // pooled A-reads done
  for (int j = 0; j < ncnt; ++j){
    int col = myn[j]*32 + lane32;
    #pragma unroll
    for (int reg = 0; reg < 4; ++reg)
      sPool[(reg + 4*hi)*AST + col] = f2b(yv[j][reg]);
  }
  __syncthreads();                            // y visible

  // ---- out1: z = (y @ out_w1^T + b1) * valid -> global fp32 ----
  {
    bf16x8 A[16];
    #pragma unroll
    for (int k = 0; k < 16; ++k)
      A[k] = *(const bf16x8*)&sPool[lane32*AST + k*16 + 8*hi];
    #pragma unroll 1
    for (int nt = w; nt < 8; nt += 5){
      const bf16* p = ow1b + (size_t)(nt*32 + lane32)*256 + 8*hi;
      f32x16 acc = {};
      #pragma unroll
      for (int k = 0; k < 16; ++k){
        bf16x8 b = *(const bf16x8*)(p + k*16);
        acc = __builtin_amdgcn_mfma_f32_32x32x16_bf16(A[k], b, acc, 0, 0, 0);
      }
      int col = nt*32 + lane32;
      #pragma unroll
      for (int reg = 0; reg < 4; ++reg){
        int r = reg + 4*hi;
        outp[(size_t)(blk*8 + r)*256 + col] = (acc[reg] + out_b1[col]) * sValidF[r];
      }
    }
  }
}

extern "C" void kernel_launch(void* const* d_in, const int* in_sizes, int n_in,
                              void* d_out, int out_size, void* d_ws, size_t ws_size,
                              hipStream_t stream)
{
  const float* poly      = (const float*)d_in[0];
  const int*   maskp     = (const int*)  d_in[1];
  const float* pre_w0    = (const float*)d_in[2];
  const float* pre_g0    = (const float*)d_in[3];
  const float* pre_b0    = (const float*)d_in[4];
  const float* pre_w1    = (const float*)d_in[5];
  const float* pre_g1    = (const float*)d_in[6];
  const float* pre_b1    = (const float*)d_in[7];
  const float* pre_w2    = (const float*)d_in[8];
  const float* pre_bias2 = (const float*)d_in[9];
  const float* mlp_w0    = (const float*)d_in[10];
  const float* mlp_g0    = (const float*)d_in[11];
  const float* mlp_b0    = (const float*)d_in[12];
  const float* mlp_w1    = (const float*)d_in[13];
  const float* mlp_g1    = (const float*)d_in[14];
  const float* mlp_b1    = (const float*)d_in[15];
  const float* mlp_w2    = (const float*)d_in[16];
  const float* mlp_bias2 = (const float*)d_in[17];
  const float* out_w0    = (const float*)d_in[18];
  const float* out_b0    = (const float*)d_in[19];
  const float* out_w1    = (const float*)d_in[20];
  const float* out_b1    = (const float*)d_in[21];

  bf16* ws = (bf16*)d_ws;   // 1,064,960 B of ws used

  (void)hipFuncSetAttribute((const void*)&traj_kernel,
                            hipFuncAttributeMaxDynamicSharedMemorySize, LDS_TOTAL);

  prep_kernel<<<dim3(64, 8), dim3(256), 0, stream>>>(
      pre_w0, pre_w1, pre_w2, mlp_w0, mlp_w1, mlp_w2, out_w0, out_w1, ws);

  traj_kernel<<<dim3(1024), dim3(320), LDS_TOTAL, stream>>>(
      poly, maskp,
      pre_g0, pre_b0, pre_g1, pre_b1, pre_bias2,
      mlp_g0, mlp_b0, mlp_g1, mlp_b1, mlp_bias2,
      out_b0, out_b1,
      ws, (float*)d_out);
}